// Round 4
// baseline (1038.676 us; speedup 1.0000x reference)
//
#include <hip/hip_runtime.h>
#include <hip/hip_bf16.h>

using u16 = unsigned short;
using u32 = unsigned int;

typedef __bf16 bf16x8 __attribute__((ext_vector_type(8)));
typedef float  f32x4  __attribute__((ext_vector_type(4)));
typedef u32    u32x4  __attribute__((ext_vector_type(4)));

__device__ __forceinline__ float bflo(u32 u){ union { u32 u; float f; } c; c.u = u << 16;          return c.f; }
__device__ __forceinline__ float bfhi(u32 u){ union { u32 u; float f; } c; c.u = u & 0xffff0000u;  return c.f; }
__device__ __forceinline__ u16  f2bf(float f){
  union { float f; u32 u; } c; c.f = f;
  u32 u = c.u;
  return (u16)((u + 0x7fffu + ((u >> 16) & 1u)) >> 16); // RNE
}

__device__ __forceinline__ void gload_lds16(const void* g, void* l){
  __builtin_amdgcn_global_load_lds(
      (const __attribute__((address_space(1))) void*)g,
      (__attribute__((address_space(3))) void*)l, 16, 0, 0);
}

// ---------------- prep: degree count, hierarchical scan, CSR, list sort, degree perm ----------------

__global__ void count_deg_kernel(const int* __restrict__ dst, int E, int* __restrict__ cnt){
  int i = blockIdx.x * blockDim.x + threadIdx.x;
  if (i < E) atomicAdd(&cnt[dst[i]], 1);
}

// per-1024-block exclusive scan; block sums out
__global__ void scan1_kernel(const int* __restrict__ cnt, int n,
                             int* __restrict__ excl, int* __restrict__ bsums){
  __shared__ int sd[1024];
  const int tid = threadIdx.x;
  const int i = blockIdx.x * 1024 + tid;
  int v = (i < n) ? cnt[i] : 0;
  sd[tid] = v;
  __syncthreads();
  for (int s = 1; s < 1024; s <<= 1){
    int t = (tid >= s) ? sd[tid - s] : 0;
    __syncthreads();
    sd[tid] += t;
    __syncthreads();
  }
  if (i < n) excl[i] = sd[tid] - v;
  if (tid == 1023) bsums[blockIdx.x] = sd[tid];
}

// exclusive scan over <=256 entries, in place
__global__ void scan2_kernel(int* __restrict__ bsums, int nb){
  __shared__ int sd[256];
  const int tid = threadIdx.x;
  int v = (tid < nb) ? bsums[tid] : 0;
  sd[tid] = v;
  __syncthreads();
  for (int s = 1; s < 256; s <<= 1){
    int t = (tid >= s) ? sd[tid - s] : 0;
    __syncthreads();
    sd[tid] += t;
    __syncthreads();
  }
  if (tid < nb) bsums[tid] = sd[tid] - v;
}

__global__ void finalize_kernel(int* __restrict__ rowptr, int* __restrict__ cursor,
                                const int* __restrict__ bsums, const int* __restrict__ cnt,
                                float* __restrict__ dis, int n, int total){
  int i = blockIdx.x * blockDim.x + threadIdx.x;
  if (i < n){
    int r = rowptr[i] + bsums[i >> 10];
    rowptr[i] = r;
    cursor[i] = r;
    dis[i] = rsqrtf((float)(cnt[i] + 1)); // +1 self loop
  }
  if (i == 0) rowptr[n] = total;
}

__global__ void fill_csr_kernel(const int* __restrict__ src, const int* __restrict__ dst,
                                int E, int* __restrict__ cursor, u16* __restrict__ col){
  int i = blockIdx.x * blockDim.x + threadIdx.x;
  if (i < E){
    int d = dst[i];
    int p = atomicAdd(&cursor[d], 1);
    col[p] = (u16)src[i];
  }
}

// sort each dst list ascending by src (perf-only: enables src-sweep locality)
#define SCAP 64
__global__ __launch_bounds__(256) void sort_lists_kernel(const int* __restrict__ rowptr,
                                                         u16* __restrict__ col, int N){
  __shared__ u16 buf[256][SCAP];
  const int v = blockIdx.x * 256 + threadIdx.x;
  if (v >= N) return;
  const int e0 = rowptr[v];
  int len = rowptr[v + 1] - e0;
  if (len > SCAP) len = SCAP;  // sort prefix only; correctness unaffected
  u16* b = buf[threadIdx.x];
  for (int i = 0; i < len; ++i) b[i] = col[e0 + i];
  for (int i = 1; i < len; ++i){
    u16 key = b[i]; int j = i - 1;
    while (j >= 0 && b[j] > key){ b[j + 1] = b[j]; --j; }
    b[j + 1] = key;
  }
  for (int i = 0; i < len; ++i) col[e0 + i] = b[i];
}

// counting sort of nodes by (clamped) degree -> perm
__global__ void hist_deg_kernel(const int* __restrict__ cnt, int N, int* __restrict__ hist){
  int i = blockIdx.x * blockDim.x + threadIdx.x;
  if (i < N) atomicAdd(&hist[min(cnt[i], 255)], 1);
}

__global__ void scatter_perm_kernel(const int* __restrict__ cnt, int N,
                                    int* __restrict__ cursor256, int* __restrict__ perm){
  int i = blockIdx.x * blockDim.x + threadIdx.x;
  if (i < N){
    int p = atomicAdd(&cursor256[min(cnt[i], 255)], 1);
    perm[p] = i;
  }
}

__global__ void convert_x_kernel(const float* __restrict__ x, u32* __restrict__ xb,
                                 int n_real, int n_tot){
  int i8 = (blockIdx.x * blockDim.x + threadIdx.x) * 8;
  if (i8 >= n_tot) return;
  u32 q0, q1, q2, q3;
  if (i8 < n_real){
    const f32x4* xp = (const f32x4*)(x + i8);
    f32x4 a = xp[0], b = xp[1];
    q0 = ((u32)f2bf(a[1]) << 16) | f2bf(a[0]);
    q1 = ((u32)f2bf(a[3]) << 16) | f2bf(a[2]);
    q2 = ((u32)f2bf(b[1]) << 16) | f2bf(b[0]);
    q3 = ((u32)f2bf(b[3]) << 16) | f2bf(b[2]);
  } else {
    q0 = q1 = q2 = q3 = 0u;
  }
  u32x4 q = {q0, q1, q2, q3};
  *(u32x4*)(xb + (i8 >> 1)) = q;
}

// Wt[l][n][k] = bf16(W[l][k][n])
__global__ void convert_w_kernel(const float* __restrict__ W, u16* __restrict__ Wt, int total){
  int i = blockIdx.x * blockDim.x + threadIdx.x;
  if (i >= total) return;
  int k = i & 511, n = (i >> 9) & 511, l = i >> 18;
  Wt[i] = f2bf(W[(l << 18) | (k << 9) | n]);
}

// ---------------- aggregation, feature-sliced across XCDs ----------------
// block b: slice = b&7 (-> XCD b&7 by round-robin), node group = b>>3.
// 256 threads = 32 node-slots x 8 lanes; each lane owns 8 features (16B).
// agg[v] = dv^2*x[v] + sum_e dis[s]*dv*x[s]   (bf16 in -> bf16 out, f32 accum)

__global__ __launch_bounds__(256) void aggregate_kernel(const u32x4* __restrict__ x4,
                                                        const int* __restrict__ rowptr,
                                                        const u16* __restrict__ col,
                                                        const float* __restrict__ dis,
                                                        const int* __restrict__ perm,
                                                        u32x4* __restrict__ o4,
                                                        int N){
  const int slice = blockIdx.x & 7;
  const int grp   = blockIdx.x >> 3;
  const int tid   = threadIdx.x;
  const int slot  = tid >> 3;
  const int fl    = tid & 7;
  const int idx   = grp * 32 + slot;
  if (idx >= N) return;
  const int v  = perm[idx];
  const int co = slice * 8 + fl;   // u32x4 chunk index within the 64-chunk row

  const float dv = dis[v];
  float acc[8];
  {
    u32x4 q = x4[(size_t)v * 64 + co]; // self loop, norm = dv*dv
    const float w = dv * dv;
    #pragma unroll
    for (int k = 0; k < 4; ++k){ acc[2*k] = w * bflo(q[k]); acc[2*k+1] = w * bfhi(q[k]); }
  }
  const int e0 = rowptr[v], e1 = rowptr[v + 1];
  int s_cur = 0; u32x4 qc = {0,0,0,0};
  if (e0 < e1){ s_cur = col[e0]; qc = x4[(size_t)s_cur * 64 + co]; }
  for (int e = e0; e < e1; ++e){
    int s_nxt = 0; u32x4 qn = {0,0,0,0};
    if (e + 1 < e1){ s_nxt = col[e + 1]; qn = x4[(size_t)s_nxt * 64 + co]; } // prefetch
    const float w = dis[s_cur] * dv;
    #pragma unroll
    for (int k = 0; k < 4; ++k){ acc[2*k] += w * bflo(qc[k]); acc[2*k+1] += w * bfhi(qc[k]); }
    s_cur = s_nxt; qc = qn;
  }

  u32x4 r;
  #pragma unroll
  for (int k = 0; k < 4; ++k)
    r[k] = ((u32)f2bf(acc[2*k+1]) << 16) | f2bf(acc[2*k]);
  o4[(size_t)v * 64 + co] = r;
}

// ---------------- GEMM: C = relu(A * W + b), fused epilogue ----------------

__global__ __launch_bounds__(256) void gemm_kernel(const u16* __restrict__ A,
                                                   const u16* __restrict__ Bt,
                                                   const float* __restrict__ bias,
                                                   u16* __restrict__ Cb,
                                                   float* __restrict__ Cf,
                                                   int n_real, int last){
  __shared__ u16 sA[2][128 * 64];
  __shared__ u16 sB[2][128 * 64];
  const int tid  = threadIdx.x;
  const int lane = tid & 63;
  const int wv   = tid >> 6;
  const int wm   = wv >> 1, wn = wv & 1;
  const int bm0  = blockIdx.x * 128;
  const int bn0  = blockIdx.y * 128;
  const int sr   = lane >> 3;
  const int sc   = (lane & 7) << 3;

  f32x4 acc[4][4] = {};

  auto stage = [&](int bsel, int t){
    const int k0 = t * 64;
    #pragma unroll
    for (int i = 0; i < 4; ++i){
      const int rr = ((wv * 4 + i) << 3) + sr;
      gload_lds16(A  + (((size_t)(bm0 + rr)) << 9) + k0 + sc, (void*)&sA[bsel][(wv * 4 + i) * 512]);
      gload_lds16(Bt + (((size_t)(bn0 + rr)) << 9) + k0 + sc, (void*)&sB[bsel][(wv * 4 + i) * 512]);
    }
  };

  stage(0, 0);
  __syncthreads();
  int cur = 0;
  const int lr = lane & 15, lg = lane >> 4;

  for (int t = 0; t < 8; ++t){
    if (t < 7) stage(cur ^ 1, t + 1);
    const bf16x8* A8 = (const bf16x8*)sA[cur];
    const bf16x8* B8 = (const bf16x8*)sB[cur];
    #pragma unroll
    for (int ks = 0; ks < 2; ++ks){
      bf16x8 af[4], bg[4];
      #pragma unroll
      for (int mi = 0; mi < 4; ++mi)
        af[mi] = A8[((wm * 64 + mi * 16 + lr) << 3) + (ks << 2) + lg];
      #pragma unroll
      for (int ni = 0; ni < 4; ++ni)
        bg[ni] = B8[((wn * 64 + ni * 16 + lr) << 3) + (ks << 2) + lg];
      #pragma unroll
      for (int mi = 0; mi < 4; ++mi)
        #pragma unroll
        for (int ni = 0; ni < 4; ++ni)
          acc[mi][ni] = __builtin_amdgcn_mfma_f32_16x16x32_bf16(af[mi], bg[ni], acc[mi][ni], 0, 0, 0);
    }
    __syncthreads();
    cur ^= 1;
  }

  float bb[4];
  #pragma unroll
  for (int ni = 0; ni < 4; ++ni) bb[ni] = bias[bn0 + wn * 64 + ni * 16 + lr];

  #pragma unroll
  for (int mi = 0; mi < 4; ++mi){
    const int row0 = bm0 + wm * 64 + mi * 16 + (lg << 2);
    #pragma unroll
    for (int ni = 0; ni < 4; ++ni){
      const int c0 = bn0 + wn * 64 + ni * 16 + lr;
      #pragma unroll
      for (int r = 0; r < 4; ++r){
        const float val = fmaxf(acc[mi][ni][r] + bb[ni], 0.f);
        if (!last){
          Cb[(((size_t)(row0 + r)) << 9) + c0] = f2bf(val);
        } else if (row0 + r < n_real){
          Cf[(((size_t)(row0 + r)) << 9) + c0] = val;
        }
      }
    }
  }
}

// ---------------- launch ----------------

extern "C" void kernel_launch(void* const* d_in, const int* in_sizes, int n_in,
                              void* d_out, int out_size, void* d_ws, size_t ws_size,
                              hipStream_t stream) {
  const float* x    = (const float*)d_in[0];
  const int*   ei   = (const int*)d_in[1];   // [2][E] int32: src = ei, dst = ei + E
  const float* W    = (const float*)d_in[2]; // [L][512][512]
  const float* bias = (const float*)d_in[3]; // [L][512]
  float* out = (float*)d_out;

  const int N = in_sizes[0] >> 9;       // 50000
  const int E = in_sizes[1] >> 1;       // 800000
  const int L = in_sizes[3] >> 9;       // 3
  const int MPAD = (N + 127) & ~127;    // 50048
  const int NB = (N + 1023) / 1024;     // scan blocks (49)

  char* p = (char*)d_ws;
  auto alloc = [&](size_t bytes){ char* q = p; p += (bytes + 255) & ~(size_t)255; return q; };
  u16*   xb       = (u16*)alloc((size_t)MPAD * 512 * 2);
  u16*   aggb     = (u16*)alloc((size_t)MPAD * 512 * 2);
  u16*   wt       = (u16*)alloc((size_t)L * 512 * 512 * 2);
  float* dis      = (float*)alloc((size_t)N * 4);
  int*   rowptr_d = (int*)alloc((size_t)(N + 1) * 4);
  int*   cursor_d = (int*)alloc((size_t)N * 4);
  int*   cnt_d    = (int*)alloc((size_t)N * 4);
  int*   perm     = (int*)alloc((size_t)N * 4);
  u16*   col      = (u16*)alloc((size_t)E * 2);
  int*   bsums_d  = (int*)alloc(256 * 4);
  int*   dhist    = (int*)alloc(256 * 4);

  hipMemsetAsync(cnt_d, 0, (size_t)N * 4, stream);
  hipMemsetAsync(dhist, 0, 256 * 4, stream);
  // zero the pad rows of aggb once; aggregate only writes rows < N
  hipMemsetAsync(aggb + (size_t)N * 512, 0, (size_t)(MPAD - N) * 512 * 2, stream);

  count_deg_kernel<<<(E + 255) / 256, 256, 0, stream>>>(ei + E, E, cnt_d);
  scan1_kernel<<<NB, 1024, 0, stream>>>(cnt_d, N, rowptr_d, bsums_d);
  scan2_kernel<<<1, 256, 0, stream>>>(bsums_d, NB);
  finalize_kernel<<<(N + 255) / 256, 256, 0, stream>>>(rowptr_d, cursor_d, bsums_d, cnt_d, dis, N, E);
  fill_csr_kernel<<<(E + 255) / 256, 256, 0, stream>>>(ei, ei + E, E, cursor_d, col);
  sort_lists_kernel<<<(N + 255) / 256, 256, 0, stream>>>(rowptr_d, col, N);

  hist_deg_kernel<<<(N + 255) / 256, 256, 0, stream>>>(cnt_d, N, dhist);
  scan2_kernel<<<1, 256, 0, stream>>>(dhist, 256);
  scatter_perm_kernel<<<(N + 255) / 256, 256, 0, stream>>>(cnt_d, N, dhist, perm);

  const int ntot = MPAD * 512;
  convert_x_kernel<<<(ntot / 8 + 255) / 256, 256, 0, stream>>>(x, (u32*)xb, N * 512, ntot);
  convert_w_kernel<<<(L * 512 * 512 + 255) / 256, 256, 0, stream>>>(W, wt, L * 512 * 512);

  const int ngrp = (N + 31) / 32;
  for (int l = 0; l < L; ++l){
    aggregate_kernel<<<ngrp * 8, 256, 0, stream>>>((const u32x4*)xb, rowptr_d, col, dis,
                                                   perm, (u32x4*)aggb, N);
    gemm_kernel<<<dim3(MPAD / 128, 4), 256, 0, stream>>>(aggb, wt + (size_t)l * 512 * 512,
                                                         bias + (size_t)l * 512,
                                                         xb, out, N, (l == L - 1) ? 1 : 0);
  }
}

// Round 5
// 687.691 us; speedup vs baseline: 1.5104x; 1.5104x over previous
//
#include <hip/hip_runtime.h>
#include <hip/hip_bf16.h>

using u16 = unsigned short;
using u32 = unsigned int;

typedef __bf16 bf16x8 __attribute__((ext_vector_type(8)));
typedef float  f32x4  __attribute__((ext_vector_type(4)));
typedef u32    u32x4  __attribute__((ext_vector_type(4)));
typedef u16    u16x4  __attribute__((ext_vector_type(4)));

__device__ __forceinline__ float bflo(u32 u){ union { u32 u; float f; } c; c.u = u << 16;          return c.f; }
__device__ __forceinline__ float bfhi(u32 u){ union { u32 u; float f; } c; c.u = u & 0xffff0000u;  return c.f; }
__device__ __forceinline__ u16  f2bf(float f){
  union { float f; u32 u; } c; c.f = f;
  u32 u = c.u;
  return (u16)((u + 0x7fffu + ((u >> 16) & 1u)) >> 16); // RNE
}

__device__ __forceinline__ void gload_lds16(const void* g, void* l){
  __builtin_amdgcn_global_load_lds(
      (const __attribute__((address_space(1))) void*)g,
      (__attribute__((address_space(3))) void*)l, 16, 0, 0);
}

// ---------------- prep: degree count, hierarchical scan (8-padded), CSR ----------------

__global__ void count_deg_kernel(const int* __restrict__ dst, int E, int* __restrict__ cnt){
  int i = blockIdx.x * blockDim.x + threadIdx.x;
  if (i < E) atomicAdd(&cnt[dst[i]], 1);
}

// per-1024-block exclusive scan of ceil8(cnt); block sums out
__global__ void scan1_kernel(const int* __restrict__ cnt, int n,
                             int* __restrict__ excl, int* __restrict__ bsums){
  __shared__ int sd[1024];
  const int tid = threadIdx.x;
  const int i = blockIdx.x * 1024 + tid;
  int v = (i < n) ? ((cnt[i] + 7) & ~7) : 0;   // pad each list to multiple of 8
  sd[tid] = v;
  __syncthreads();
  for (int s = 1; s < 1024; s <<= 1){
    int t = (tid >= s) ? sd[tid - s] : 0;
    __syncthreads();
    sd[tid] += t;
    __syncthreads();
  }
  if (i < n) excl[i] = sd[tid] - v;
  if (tid == 1023) bsums[blockIdx.x] = sd[tid];
}

// exclusive scan over <=255 entries, in place; inclusive total -> bsums[nb]
__global__ void scan2_kernel(int* __restrict__ bsums, int nb){
  __shared__ int sd[256];
  const int tid = threadIdx.x;
  int v = (tid < nb) ? bsums[tid] : 0;
  sd[tid] = v;
  __syncthreads();
  for (int s = 1; s < 256; s <<= 1){
    int t = (tid >= s) ? sd[tid - s] : 0;
    __syncthreads();
    sd[tid] += t;
    __syncthreads();
  }
  if (tid < nb) bsums[tid] = sd[tid] - v;
  if (tid == nb - 1) bsums[nb] = sd[tid];    // total padded edge count
}

__global__ void finalize_kernel(int* __restrict__ rowptr, int* __restrict__ cursor,
                                const int* __restrict__ bsums, int nb,
                                const int* __restrict__ cnt,
                                float* __restrict__ dis, int n){
  int i = blockIdx.x * blockDim.x + threadIdx.x;
  if (i < n){
    int r = rowptr[i] + bsums[i >> 10];
    rowptr[i] = r;
    cursor[i] = r;
    dis[i] = rsqrtf((float)(cnt[i] + 1)); // +1 self loop
  }
  if (i == 0){
    rowptr[n] = bsums[nb];
    dis[n] = 0.f;                          // sentinel node: zero weight
  }
}

__global__ void fill_csr_kernel(const int* __restrict__ src, const int* __restrict__ dst,
                                int E, int* __restrict__ cursor, u16* __restrict__ col){
  int i = blockIdx.x * blockDim.x + threadIdx.x;
  if (i < E){
    int d = dst[i];
    int p = atomicAdd(&cursor[d], 1);
    col[p] = (u16)src[i];
  }
}

// fill per-list padding (and 8 sentinel slots past the end) with node N
__global__ void pad_fill_kernel(const int* __restrict__ rowptr, const int* __restrict__ cnt,
                                int N, u16* __restrict__ col){
  int v = blockIdx.x * blockDim.x + threadIdx.x;
  if (v < N){
    int p = rowptr[v] + cnt[v];
    const int p1 = rowptr[v + 1];
    for (; p < p1; ++p) col[p] = (u16)N;
  }
  if (v == 0){
    int t = rowptr[N];
    for (int j = 0; j < 8; ++j) col[t + j] = (u16)N;
  }
}

__global__ void convert_x_kernel(const float* __restrict__ x, u32* __restrict__ xb,
                                 int n_real, int n_tot){
  int i8 = (blockIdx.x * blockDim.x + threadIdx.x) * 8;
  if (i8 >= n_tot) return;
  u32 q0, q1, q2, q3;
  if (i8 < n_real){
    const f32x4* xp = (const f32x4*)(x + i8);
    f32x4 a = xp[0], b = xp[1];
    q0 = ((u32)f2bf(a[1]) << 16) | f2bf(a[0]);
    q1 = ((u32)f2bf(a[3]) << 16) | f2bf(a[2]);
    q2 = ((u32)f2bf(b[1]) << 16) | f2bf(b[0]);
    q3 = ((u32)f2bf(b[3]) << 16) | f2bf(b[2]);
  } else {
    q0 = q1 = q2 = q3 = 0u;  // pad rows (incl. sentinel row N) stay zero
  }
  u32x4 q = {q0, q1, q2, q3};
  *(u32x4*)(xb + (i8 >> 1)) = q;
}

// Wt[l][n][k] = bf16(W[l][k][n])
__global__ void convert_w_kernel(const float* __restrict__ W, u16* __restrict__ Wt, int total){
  int i = blockIdx.x * blockDim.x + threadIdx.x;
  if (i >= total) return;
  int k = i & 511, n = (i >> 9) & 511, l = i >> 18;
  Wt[i] = f2bf(W[(l << 18) | (k << 9) | n]);
}

// ---------------- aggregation: one wave per node, 4-deep double-buffered gather pipeline ----
// agg[v] = dv^2*x[v] + sum_e dis[s]*dv*x[s]   (bf16 in -> bf16 out, f32 accum)
// lists are padded to multiples of 8 with sentinel N (x[N]=0, dis[N]=0).

__global__ __launch_bounds__(256) void aggregate_kernel(const u32x4* __restrict__ x4,
                                                        const int* __restrict__ rowptr,
                                                        const u16* __restrict__ col,
                                                        const float* __restrict__ dis,
                                                        u32x4* __restrict__ o4,
                                                        int N){
  const int lane = threadIdx.x & 63;
  const int v = blockIdx.x * 4 + (threadIdx.x >> 6);
  if (v >= N) return;

  const float dv = dis[v];
  float acc[8];
  {
    u32x4 q = x4[(size_t)v * 64 + lane]; // self loop, norm = dv*dv
    const float w = dv * dv;
    #pragma unroll
    for (int k = 0; k < 4; ++k){ acc[2*k] = w * bflo(q[k]); acc[2*k+1] = w * bfhi(q[k]); }
  }

  auto fmacc = [&](const u32x4& q, float w){
    #pragma unroll
    for (int k = 0; k < 4; ++k){ acc[2*k] += w * bflo(q[k]); acc[2*k+1] += w * bfhi(q[k]); }
  };

  const int e0 = rowptr[v];
  const int m  = (rowptr[v + 1] - e0) >> 3;   // number of 8-edge pairs (len % 8 == 0)
  const u16* cp = col + e0;

  // prologue: batch A in flight
  u16x4 sA = *(const u16x4*)cp;
  u32x4 qA0 = x4[(size_t)sA[0] * 64 + lane];
  u32x4 qA1 = x4[(size_t)sA[1] * 64 + lane];
  u32x4 qA2 = x4[(size_t)sA[2] * 64 + lane];
  u32x4 qA3 = x4[(size_t)sA[3] * 64 + lane];

  for (int i = 0; i < m; ++i){
    // issue batch B
    u16x4 sB = *(const u16x4*)(cp + 8 * i + 4);
    u32x4 qB0 = x4[(size_t)sB[0] * 64 + lane];
    u32x4 qB1 = x4[(size_t)sB[1] * 64 + lane];
    u32x4 qB2 = x4[(size_t)sB[2] * 64 + lane];
    u32x4 qB3 = x4[(size_t)sB[3] * 64 + lane];
    // consume batch A
    {
      float w0 = dis[sA[0]] * dv, w1 = dis[sA[1]] * dv;
      float w2 = dis[sA[2]] * dv, w3 = dis[sA[3]] * dv;
      fmacc(qA0, w0); fmacc(qA1, w1); fmacc(qA2, w2); fmacc(qA3, w3);
    }
    // issue next batch A (reads <= 4 u16 past the last list end -> sentinel slack)
    sA = *(const u16x4*)(cp + 8 * i + 8);
    qA0 = x4[(size_t)sA[0] * 64 + lane];
    qA1 = x4[(size_t)sA[1] * 64 + lane];
    qA2 = x4[(size_t)sA[2] * 64 + lane];
    qA3 = x4[(size_t)sA[3] * 64 + lane];
    // consume batch B
    {
      float w0 = dis[sB[0]] * dv, w1 = dis[sB[1]] * dv;
      float w2 = dis[sB[2]] * dv, w3 = dis[sB[3]] * dv;
      fmacc(qB0, w0); fmacc(qB1, w1); fmacc(qB2, w2); fmacc(qB3, w3);
    }
  }

  u32x4 r;
  #pragma unroll
  for (int k = 0; k < 4; ++k)
    r[k] = ((u32)f2bf(acc[2*k+1]) << 16) | f2bf(acc[2*k]);
  o4[(size_t)v * 64 + lane] = r;
}

// ---------------- GEMM: C = relu(A * W + b), fused epilogue, XCD-chunked swizzle --------
// 1D grid of (M/128)*4 blocks; same-A-row blocks co-resident per XCD (m204 bijective map).

__global__ __launch_bounds__(256) void gemm_kernel(const u16* __restrict__ A,
                                                   const u16* __restrict__ Bt,
                                                   const float* __restrict__ bias,
                                                   u16* __restrict__ Cb,
                                                   float* __restrict__ Cf,
                                                   int n_real, int last){
  __shared__ u16 sA[2][128 * 64];
  __shared__ u16 sB[2][128 * 64];

  // bijective XCD-chunk swizzle: blocks orig%8==xcd get a contiguous range of logical wg
  const int nwg  = gridDim.x;
  const int q8   = nwg >> 3, r8 = nwg & 7;
  const int xcd  = blockIdx.x & 7, oi = blockIdx.x >> 3;
  const int wg   = ((xcd < r8) ? xcd * (q8 + 1) : r8 * (q8 + 1) + (xcd - r8) * q8) + oi;
  const int bm0  = (wg >> 2) * 128;   // bn fastest: 4 col-blocks of one row-band adjacent
  const int bn0  = (wg & 3) * 128;

  const int tid  = threadIdx.x;
  const int lane = tid & 63;
  const int wv   = tid >> 6;
  const int wm   = wv >> 1, wn = wv & 1;
  const int sr   = lane >> 3;
  const int sc   = (lane & 7) << 3;

  f32x4 acc[4][4] = {};

  auto stage = [&](int bsel, int t){
    const int k0 = t * 64;
    #pragma unroll
    for (int i = 0; i < 4; ++i){
      const int rr = ((wv * 4 + i) << 3) + sr;
      gload_lds16(A  + (((size_t)(bm0 + rr)) << 9) + k0 + sc, (void*)&sA[bsel][(wv * 4 + i) * 512]);
      gload_lds16(Bt + (((size_t)(bn0 + rr)) << 9) + k0 + sc, (void*)&sB[bsel][(wv * 4 + i) * 512]);
    }
  };

  stage(0, 0);
  __syncthreads();
  int cur = 0;
  const int lr = lane & 15, lg = lane >> 4;

  for (int t = 0; t < 8; ++t){
    if (t < 7) stage(cur ^ 1, t + 1);
    const bf16x8* A8 = (const bf16x8*)sA[cur];
    const bf16x8* B8 = (const bf16x8*)sB[cur];
    #pragma unroll
    for (int ks = 0; ks < 2; ++ks){
      bf16x8 af[4], bg[4];
      #pragma unroll
      for (int mi = 0; mi < 4; ++mi)
        af[mi] = A8[((wm * 64 + mi * 16 + lr) << 3) + (ks << 2) + lg];
      #pragma unroll
      for (int ni = 0; ni < 4; ++ni)
        bg[ni] = B8[((wn * 64 + ni * 16 + lr) << 3) + (ks << 2) + lg];
      #pragma unroll
      for (int mi = 0; mi < 4; ++mi)
        #pragma unroll
        for (int ni = 0; ni < 4; ++ni)
          acc[mi][ni] = __builtin_amdgcn_mfma_f32_16x16x32_bf16(af[mi], bg[ni], acc[mi][ni], 0, 0, 0);
    }
    __syncthreads();
    cur ^= 1;
  }

  float bb[4];
  #pragma unroll
  for (int ni = 0; ni < 4; ++ni) bb[ni] = bias[bn0 + wn * 64 + ni * 16 + lr];

  // C/D layout: col=lane&15, row=(lane>>4)*4+reg  [m89-verified]
  #pragma unroll
  for (int mi = 0; mi < 4; ++mi){
    const int row0 = bm0 + wm * 64 + mi * 16 + (lg << 2);
    #pragma unroll
    for (int ni = 0; ni < 4; ++ni){
      const int c0 = bn0 + wn * 64 + ni * 16 + lr;
      #pragma unroll
      for (int r = 0; r < 4; ++r){
        const float val = fmaxf(acc[mi][ni][r] + bb[ni], 0.f);
        if (!last){
          Cb[(((size_t)(row0 + r)) << 9) + c0] = f2bf(val);
        } else if (row0 + r < n_real){
          Cf[(((size_t)(row0 + r)) << 9) + c0] = val;
        }
      }
    }
  }
}

// ---------------- launch ----------------

extern "C" void kernel_launch(void* const* d_in, const int* in_sizes, int n_in,
                              void* d_out, int out_size, void* d_ws, size_t ws_size,
                              hipStream_t stream) {
  const float* x    = (const float*)d_in[0];
  const int*   ei   = (const int*)d_in[1];   // [2][E] int32: src = ei, dst = ei + E
  const float* W    = (const float*)d_in[2]; // [L][512][512]
  const float* bias = (const float*)d_in[3]; // [L][512]
  float* out = (float*)d_out;

  const int N = in_sizes[0] >> 9;       // 50000
  const int E = in_sizes[1] >> 1;       // 800000
  const int L = in_sizes[3] >> 9;       // 3
  const int MPAD = (N + 127) & ~127;    // 50048 (> N, so row N is a zero pad row)
  const int NB = (N + 1023) / 1024;     // scan blocks (49)

  char* p = (char*)d_ws;
  auto alloc = [&](size_t bytes){ char* q = p; p += (bytes + 255) & ~(size_t)255; return q; };
  u16*   xb       = (u16*)alloc((size_t)MPAD * 512 * 2);
  u16*   aggb     = (u16*)alloc((size_t)MPAD * 512 * 2);
  u16*   wt       = (u16*)alloc((size_t)L * 512 * 512 * 2);
  float* dis      = (float*)alloc((size_t)(N + 1) * 4);
  int*   rowptr_d = (int*)alloc((size_t)(N + 1) * 4);
  int*   cursor_d = (int*)alloc((size_t)N * 4);
  int*   cnt_d    = (int*)alloc((size_t)N * 4);
  u16*   col      = (u16*)alloc(((size_t)E + 8 * (size_t)N + 16) * 2);
  int*   bsums_d  = (int*)alloc(256 * 4);

  hipMemsetAsync(cnt_d, 0, (size_t)N * 4, stream);
  // zero the pad rows of aggb once per call; aggregate only writes rows < N
  hipMemsetAsync(aggb + (size_t)N * 512, 0, (size_t)(MPAD - N) * 512 * 2, stream);

  count_deg_kernel<<<(E + 255) / 256, 256, 0, stream>>>(ei + E, E, cnt_d);
  scan1_kernel<<<NB, 1024, 0, stream>>>(cnt_d, N, rowptr_d, bsums_d);
  scan2_kernel<<<1, 256, 0, stream>>>(bsums_d, NB);
  finalize_kernel<<<(N + 255) / 256, 256, 0, stream>>>(rowptr_d, cursor_d, bsums_d, NB, cnt_d, dis, N);
  fill_csr_kernel<<<(E + 255) / 256, 256, 0, stream>>>(ei, ei + E, E, cursor_d, col);
  pad_fill_kernel<<<(N + 255) / 256, 256, 0, stream>>>(rowptr_d, cnt_d, N, col);

  const int ntot = MPAD * 512;
  convert_x_kernel<<<(ntot / 8 + 255) / 256, 256, 0, stream>>>(x, (u32*)xb, N * 512, ntot);
  convert_w_kernel<<<(L * 512 * 512 + 255) / 256, 256, 0, stream>>>(W, wt, L * 512 * 512);

  for (int l = 0; l < L; ++l){
    aggregate_kernel<<<(N + 3) / 4, 256, 0, stream>>>((const u32x4*)xb, rowptr_d, col, dis,
                                                      (u32x4*)aggb, N);
    gemm_kernel<<<(MPAD / 128) * 4, 256, 0, stream>>>(aggb, wt + (size_t)l * 512 * 512,
                                                      bias + (size_t)l * 512,
                                                      xb, out, N, (l == L - 1) ? 1 : 0);
  }
}